// Round 13
// baseline (159.474 us; speedup 1.0000x reference)
//
#include <hip/hip_runtime.h>

#define N_NODES 5000
#define N_EDGES 160000
#define HID 64
#define BATCH 512
#define NSL 64                 // sort slices (one per lane in layer1)
#define EPS (N_EDGES / NSL)    // 2500 edges per slice
#define SLOTS 12               // per-(node,slice) cap: Poisson(0.5), P(>12)~5e-13
#define NROW (NSL * SLOTS)     // 768 ints = 3 KB per node row
#define CSTRIDE 96             // compacted list stride (mean 32, +11 sigma)
#define HALF (N_NODES / 2)     // 2500

// ws layout (bytes):
//   0         slots    5000*64*12 i32  = 15,360,000   node-major: [n*768 + s*12 + q]
//   15360000  cnt      64*5000 i32     =  1,280,000   cnt[s][n] (coalesced write)
//   16640000  xpart    64*5000 f32x4   =  5,120,000   xpart[s][n] per-slice x-sums
//   21760000  compact  5000*96 i32     =  1,920,000
//   23680000  deg      5000 i32
//   23700000  h1       5000*64 f32     =  1,280,000
//   24980000  h_part   5000*64 f32     =  1,280,000
//   26260000  t_part   512*64 f32      =    131,072
//   26391072  Wl1T(256) Wr1T(256) Wl2T(4096) Wr2T(4096) Wc1hT(4096) f32

// ---------- dispatch 1: slice sort + per-slice x-sums + transposes + task MLP ----------
__global__ __launch_bounds__(256) void sort_kernel(
        const int* __restrict__ ei, const float* __restrict__ x,
        const float* __restrict__ task_feat,
        const float* __restrict__ Wt1, const float* __restrict__ bt1,
        const float* __restrict__ Wt2, const float* __restrict__ bt2,
        const float* __restrict__ Wc1, const float* __restrict__ bc1,
        const float* __restrict__ Wl1, const float* __restrict__ Wr1,
        const float* __restrict__ Wl2, const float* __restrict__ Wr2,
        int* __restrict__ slots, int* __restrict__ cnt, float4* __restrict__ xpart,
        float* __restrict__ t_part,
        float* __restrict__ Wl1T, float* __restrict__ Wr1T,
        float* __restrict__ Wl2T, float* __restrict__ Wr2T,
        float* __restrict__ Wc1hT) {
    int tid = threadIdx.x;
    int blk = blockIdx.x;
    __shared__ union SM {
        struct { int cur[HALF]; float4 xs[HALF]; } a;     // 10 KB + 40 KB (sort blocks)
        struct { float s1[4][64]; float s2[4][64]; } t;   // 2 KB (task blocks)
    } sm;

    if (blk < NSL) {
        int s = blk;
        int base = s * EPS;
        // two half-node passes so cur[] + float4 xs[] fit in LDS
        for (int half = 0; half < 2; half++) {
            int n0 = half * HALF;
            for (int i = tid; i < HALF; i += 256) {
                sm.a.cur[i] = 0;
                sm.a.xs[i] = make_float4(0.f, 0.f, 0.f, 0.f);
            }
            __syncthreads();
            for (int j = tid; j < EPS; j += 256) {
                int src = ei[base + j];
                int dst = ei[N_EDGES + base + j];
                unsigned r = (unsigned)(dst - n0);
                if (r < (unsigned)HALF) {
                    int q = atomicAdd(&sm.a.cur[r], 1);       // LDS atomic
                    if (q < SLOTS) slots[dst * NROW + s * SLOTS + q] = src;
                    float4 xv = ((const float4*)x)[src];
                    atomicAdd(&sm.a.xs[r].x, xv.x);
                    atomicAdd(&sm.a.xs[r].y, xv.y);
                    atomicAdd(&sm.a.xs[r].z, xv.z);
                    atomicAdd(&sm.a.xs[r].w, xv.w);
                }
            }
            __syncthreads();
            for (int i = tid; i < HALF; i += 256) {
                cnt[s * N_NODES + n0 + i] = min(sm.a.cur[i], SLOTS);
                xpart[s * N_NODES + n0 + i] = sm.a.xs[i];     // coalesced 40 KB
            }
            __syncthreads();
        }
    } else if (blk < NSL + 4) {
        int w = blk - NSL;
        if (w == 0) {
            for (int idx = tid; idx < 4096; idx += 256) {
                int k = idx >> 6, h = idx & 63;
                Wl2T[idx] = Wl2[h * 64 + k];
            }
        } else if (w == 1) {
            for (int idx = tid; idx < 4096; idx += 256) {
                int k = idx >> 6, h = idx & 63;
                Wr2T[idx] = Wr2[h * 64 + k];
            }
        } else if (w == 2) {
            for (int idx = tid; idx < 4096; idx += 256) {
                int k = idx >> 6, h = idx & 63;
                Wc1hT[idx] = Wc1[h * 128 + k];
            }
        } else {
            int k = tid >> 6, h = tid & 63;
            Wl1T[tid] = Wl1[h * 4 + k];
            Wr1T[tid] = Wr1[h * 4 + k];
        }
    } else {
        // task MLP + t-half of classifier: 4 batch rows per block
        int grp = tid >> 6, h = tid & 63;
        int b = (blk - (NSL + 4)) * 4 + grp;
        float4 tf = ((const float4*)task_feat)[b];
        float4 w1 = ((const float4*)Wt1)[h];
        float v = bt1[h] + tf.x * w1.x + tf.y * w1.y + tf.z * w1.z + tf.w * w1.w;
        sm.t.s1[grp][h] = fmaxf(v, 0.f);
        __syncthreads();
        const float4* w2r = (const float4*)(Wt2 + h * 64);
        const float4* s1v = (const float4*)sm.t.s1[grp];
        float v2 = bt2[h];
#pragma unroll
        for (int q = 0; q < 16; q++) {
            float4 w = w2r[q]; float4 ss = s1v[q];
            v2 += ss.x * w.x + ss.y * w.y + ss.z * w.z + ss.w * w.w;
        }
        sm.t.s2[grp][h] = v2;             // no relu on 2nd task layer
        __syncthreads();
        const float4* wcr = (const float4*)(Wc1 + h * 128 + 64);
        const float4* s2v = (const float4*)sm.t.s2[grp];
        float p = bc1[h];
#pragma unroll
        for (int q = 0; q < 16; q++) {
            float4 w = wcr[q]; float4 ss = s2v[q];
            p += ss.x * w.x + ss.y * w.y + ss.z * w.z + ss.w * w.w;
        }
        t_part[b * 64 + h] = p;
    }
}

// ---------- dispatch 2: layer 1 (4->64), pure streaming (no dependent gathers) ----------
__global__ __launch_bounds__(256) void layer1_kernel(
        const float* __restrict__ x, const int* __restrict__ slots,
        const int* __restrict__ cnt, const float4* __restrict__ xpart,
        const float* __restrict__ Wl1T, const float* __restrict__ bl1,
        const float* __restrict__ Wr1T,
        int* __restrict__ deg, int* __restrict__ compact, float* __restrict__ h1) {
    int lane = threadIdx.x & 63, grp = threadIdx.x >> 6;
    int n = blockIdx.x * 4 + grp;
    int c = cnt[lane * N_NODES + n];             // 64 parallel 4B loads (full lines/block)
    int scan = c;                                // inclusive shuffle scan
#pragma unroll
    for (int off = 1; off < 64; off <<= 1) {
        int nb = __shfl_up(scan, off);
        if (lane >= off) scan += nb;
    }
    int d = __shfl(scan, 63);                    // total degree
    int excl = scan - c;                         // this lane's chunk offset
    const int* chunk = slots + n * NROW + lane * SLOTS;   // wave spans contiguous 3 KB
    for (int q = 0; q < c; q++) {                // copy chunk -> compacted list
        int pos = excl + q;
        if (pos < CSTRIDE) compact[n * CSTRIDE + pos] = chunk[q];
    }
    float4 xs = xpart[lane * N_NODES + n];       // per-slice partial (precomputed)
#pragma unroll
    for (int off = 1; off < 64; off <<= 1) {     // butterfly reduce float4
        xs.x += __shfl_xor(xs.x, off);
        xs.y += __shfl_xor(xs.y, off);
        xs.z += __shfl_xor(xs.z, off);
        xs.w += __shfl_xor(xs.w, off);
    }
    if (d > CSTRIDE) d = CSTRIDE;
    if (lane == 0) deg[n] = d;
    float inv = 1.f / fmaxf((float)d, 1.f);
    float m0 = xs.x * inv, m1 = xs.y * inv, m2 = xs.z * inv, m3 = xs.w * inv;
    float4 xn = ((const float4*)x)[n];
    float v = bl1[lane]
            + m0 * Wl1T[lane] + m1 * Wl1T[64 + lane]
            + m2 * Wl1T[128 + lane] + m3 * Wl1T[192 + lane]
            + xn.x * Wr1T[lane] + xn.y * Wr1T[64 + lane]
            + xn.z * Wr1T[128 + lane] + xn.w * Wr1T[192 + lane];
    h1[n * 64 + lane] = fmaxf(v, 0.f);
}

// ---------- dispatch 3: layer 2 (64->64) fused with h_part (R10 version) ----------
__global__ __launch_bounds__(256) void layer2_kernel(
        const float* __restrict__ h1, const int* __restrict__ deg,
        const int* __restrict__ compact,
        const float* __restrict__ Wl2T, const float* __restrict__ bl2,
        const float* __restrict__ Wr2T, const float* __restrict__ Wc1hT,
        float* __restrict__ h_part) {
    int h = threadIdx.x & 63, grp = threadIdx.x >> 6;
    int n = blockIdx.x * 4 + grp;
    int d = deg[n];
    const int* bucket = compact + n * CSTRIDE;
    float a0 = 0.f, a1 = 0.f, a2 = 0.f, a3 = 0.f;
    int j = 0;
    for (; j + 4 <= d; j += 4) {
        int e0 = bucket[j], e1 = bucket[j + 1], e2 = bucket[j + 2], e3 = bucket[j + 3];
        a0 += h1[e0 * 64 + h];
        a1 += h1[e1 * 64 + h];
        a2 += h1[e2 * 64 + h];
        a3 += h1[e3 * 64 + h];
    }
    for (; j < d; j++) a0 += h1[bucket[j] * 64 + h];
    float m = (a0 + a1 + a2 + a3) / fmaxf((float)d, 1.f);

    __shared__ float shm[4][64], shh[4][64], shh2[4][64];
    shm[grp][h] = m;
    shh[grp][h] = h1[n * 64 + h];
    __syncthreads();
    float v = bl2[h];
#pragma unroll
    for (int k = 0; k < 64; k++)
        v += shm[grp][k] * Wl2T[k * 64 + h] + shh[grp][k] * Wr2T[k * 64 + h];
    shh2[grp][h] = fmaxf(v, 0.f);
    __syncthreads();
    float p = 0.f;
#pragma unroll
    for (int k = 0; k < 64; k++) p += shh2[grp][k] * Wc1hT[k * 64 + h];
    h_part[n * 64 + h] = p;
}

// ---------- dispatch 4: scores[b,n] = sum_h relu(hp[n,h]+tp[b,h])*Wc2[h] + bc2 ----------
__global__ __launch_bounds__(256) void scores_kernel(
        const float* __restrict__ h_part, const float* __restrict__ t_part,
        const float* __restrict__ Wc2, const float* __restrict__ bc2,
        float* __restrict__ out) {
    int tid = threadIdx.x;
    int n = blockIdx.x * 256 + tid;
    bool valid = n < N_NODES;
    int nn = valid ? n : (N_NODES - 1);
    float hr[64];
    const float4* hp = (const float4*)(h_part + nn * 64);
#pragma unroll
    for (int i = 0; i < 16; i++) {
        float4 v = hp[i];
        hr[4 * i + 0] = v.x; hr[4 * i + 1] = v.y;
        hr[4 * i + 2] = v.z; hr[4 * i + 3] = v.w;
    }
    float b2 = bc2[0];
    int b0 = blockIdx.y * 8;
    for (int bb = 0; bb < 8; bb++) {
        const float* tp = t_part + (b0 + bb) * 64;   // wave-uniform -> scalar loads
        float acc = 0.f;
#pragma unroll
        for (int h = 0; h < 64; h++)
            acc = fmaf(fmaxf(hr[h] + tp[h], 0.f), Wc2[h], acc);
        if (valid) out[(b0 + bb) * N_NODES + n] = acc + b2;   // 1 KB per wave, coalesced
    }
}

// ---------- launch ----------
extern "C" void kernel_launch(void* const* d_in, const int* in_sizes, int n_in,
                              void* d_out, int out_size, void* d_ws, size_t ws_size,
                              hipStream_t stream) {
    const float* x    = (const float*)d_in[0];
    const int*   ei   = (const int*)d_in[1];
    const float* task = (const float*)d_in[2];
    const float* Wl1  = (const float*)d_in[3];
    const float* bl1  = (const float*)d_in[4];
    const float* Wr1  = (const float*)d_in[5];
    const float* Wl2  = (const float*)d_in[6];
    const float* bl2  = (const float*)d_in[7];
    const float* Wr2  = (const float*)d_in[8];
    const float* Wt1  = (const float*)d_in[9];
    const float* bt1  = (const float*)d_in[10];
    const float* Wt2  = (const float*)d_in[11];
    const float* bt2  = (const float*)d_in[12];
    const float* Wc1  = (const float*)d_in[13];
    const float* bc1  = (const float*)d_in[14];
    const float* Wc2  = (const float*)d_in[15];
    const float* bc2  = (const float*)d_in[16];
    float* out = (float*)d_out;

    char* ws = (char*)d_ws;
    int*    slots   = (int*)(ws + 0);
    int*    cnt     = (int*)(ws + 15360000);
    float4* xpart   = (float4*)(ws + 16640000);
    int*    compact = (int*)(ws + 21760000);
    int*    deg     = (int*)(ws + 23680000);
    float*  h1      = (float*)(ws + 23700000);
    float*  h_part  = (float*)(ws + 24980000);
    float*  t_part  = (float*)(ws + 26260000);
    float* Wl1T  = (float*)(ws + 26391072);
    float* Wr1T  = (float*)(ws + 26392096);
    float* Wl2T  = (float*)(ws + 26393120);
    float* Wr2T  = (float*)(ws + 26409504);
    float* Wc1hT = (float*)(ws + 26425888);

    sort_kernel<<<NSL + 4 + BATCH / 4, 256, 0, stream>>>(
        ei, x, task, Wt1, bt1, Wt2, bt2, Wc1, bc1, Wl1, Wr1, Wl2, Wr2,
        slots, cnt, xpart, t_part, Wl1T, Wr1T, Wl2T, Wr2T, Wc1hT);
    layer1_kernel<<<N_NODES / 4, 256, 0, stream>>>(x, slots, cnt, xpart, Wl1T, bl1, Wr1T,
                                                   deg, compact, h1);
    layer2_kernel<<<N_NODES / 4, 256, 0, stream>>>(h1, deg, compact, Wl2T, bl2, Wr2T,
                                                   Wc1hT, h_part);
    scores_kernel<<<dim3(20, 64), 256, 0, stream>>>(h_part, t_part, Wc2, bc2, out);
}

// Round 14
// 147.297 us; speedup vs baseline: 1.0827x; 1.0827x over previous
//
#include <hip/hip_runtime.h>

#define N_NODES 5000
#define N_EDGES 160000
#define HID 64
#define BATCH 512
#define NSL 64                 // sort slices (one per lane in layer1)
#define EPS (N_EDGES / NSL)    // 2500 edges per slice
#define SLOTS 12               // per-(node,slice) cap: Poisson(0.5), P(>12)~5e-13
#define NROW (NSL * SLOTS)     // 768 ints = 3 KB per node row
#define CSTRIDE 96             // compacted list stride (mean 32, +11 sigma)

// ws layout (bytes):
//   0         slots    5000*64*12 i32 = 15,360,000   node-major: [n*768 + s*12 + q]
//   15360000  cnt      64*5000 i32    =  1,280,000   cnt[s][n] (coalesced write)
//   16640000  compact  5000*96 i32    =  1,920,000
//   18560000  deg      5000 i32
//   18580000  h1       5000*64 f32    =  1,280,000
//   19860000  h_part   5000*64 f32    =  1,280,000
//   21140000  t_part   512*64 f32     =    131,072
//   21271072  Wl1T(256) Wr1T(256) Wl2T(4096) Wr2T(4096) Wc1hT(4096) f32

// ---------- dispatch 1: slice sort + weight transposes + task MLP ----------
__global__ __launch_bounds__(256) void sort_kernel(
        const int* __restrict__ ei, const float* __restrict__ task_feat,
        const float* __restrict__ Wt1, const float* __restrict__ bt1,
        const float* __restrict__ Wt2, const float* __restrict__ bt2,
        const float* __restrict__ Wc1, const float* __restrict__ bc1,
        const float* __restrict__ Wl1, const float* __restrict__ Wr1,
        const float* __restrict__ Wl2, const float* __restrict__ Wr2,
        int* __restrict__ slots, int* __restrict__ cnt, float* __restrict__ t_part,
        float* __restrict__ Wl1T, float* __restrict__ Wr1T,
        float* __restrict__ Wl2T, float* __restrict__ Wr2T,
        float* __restrict__ Wc1hT) {
    int tid = threadIdx.x;
    int blk = blockIdx.x;
    __shared__ union SM {
        int cur[N_NODES];                                 // 20 KB (sort blocks)
        struct { float s1[4][64]; float s2[4][64]; } t;   // 2 KB (task blocks)
    } sm;

    if (blk < NSL) {
        int s = blk;
        for (int i = tid; i < N_NODES; i += 256) sm.cur[i] = 0;
        __syncthreads();
        int base = s * EPS;
        for (int j = tid; j < EPS; j += 256) {
            int src = ei[base + j];
            int dst = ei[N_EDGES + base + j];
            int q = atomicAdd(&sm.cur[dst], 1);           // LDS atomic
            if (q < SLOTS) slots[dst * NROW + s * SLOTS + q] = src;
        }
        __syncthreads();
        for (int n = tid; n < N_NODES; n += 256)
            cnt[s * N_NODES + n] = min(sm.cur[n], SLOTS); // coalesced row write
    } else if (blk < NSL + 4) {
        int w = blk - NSL;
        if (w == 0) {
            for (int idx = tid; idx < 4096; idx += 256) {
                int k = idx >> 6, h = idx & 63;
                Wl2T[idx] = Wl2[h * 64 + k];
            }
        } else if (w == 1) {
            for (int idx = tid; idx < 4096; idx += 256) {
                int k = idx >> 6, h = idx & 63;
                Wr2T[idx] = Wr2[h * 64 + k];
            }
        } else if (w == 2) {
            for (int idx = tid; idx < 4096; idx += 256) {
                int k = idx >> 6, h = idx & 63;
                Wc1hT[idx] = Wc1[h * 128 + k];
            }
        } else {
            int k = tid >> 6, h = tid & 63;
            Wl1T[tid] = Wl1[h * 4 + k];
            Wr1T[tid] = Wr1[h * 4 + k];
        }
    } else {
        // task MLP + t-half of classifier: 4 batch rows per block
        int grp = tid >> 6, h = tid & 63;
        int b = (blk - (NSL + 4)) * 4 + grp;
        float4 tf = ((const float4*)task_feat)[b];
        float4 w1 = ((const float4*)Wt1)[h];
        float v = bt1[h] + tf.x * w1.x + tf.y * w1.y + tf.z * w1.z + tf.w * w1.w;
        sm.t.s1[grp][h] = fmaxf(v, 0.f);
        __syncthreads();
        const float4* w2r = (const float4*)(Wt2 + h * 64);
        const float4* s1v = (const float4*)sm.t.s1[grp];
        float v2 = bt2[h];
#pragma unroll
        for (int q = 0; q < 16; q++) {
            float4 w = w2r[q]; float4 ss = s1v[q];
            v2 += ss.x * w.x + ss.y * w.y + ss.z * w.z + ss.w * w.w;
        }
        sm.t.s2[grp][h] = v2;             // no relu on 2nd task layer
        __syncthreads();
        const float4* wcr = (const float4*)(Wc1 + h * 128 + 64);
        const float4* s2v = (const float4*)sm.t.s2[grp];
        float p = bc1[h];
#pragma unroll
        for (int q = 0; q < 16; q++) {
            float4 w = wcr[q]; float4 ss = s2v[q];
            p += ss.x * w.x + ss.y * w.y + ss.z * w.z + ss.w * w.w;
        }
        t_part[b * 64 + h] = p;
    }
}

// ---------- dispatch 2: layer 1 (4->64), lane-parallel: lane l owns slice l ----------
__global__ __launch_bounds__(256) void layer1_kernel(
        const float* __restrict__ x, const int* __restrict__ slots,
        const int* __restrict__ cnt,
        const float* __restrict__ Wl1T, const float* __restrict__ bl1,
        const float* __restrict__ Wr1T,
        int* __restrict__ deg, int* __restrict__ compact, float* __restrict__ h1) {
    int lane = threadIdx.x & 63, grp = threadIdx.x >> 6;
    int n = blockIdx.x * 4 + grp;
    int c = cnt[lane * N_NODES + n];             // 64 parallel 4B loads
    int scan = c;                                // inclusive shuffle scan
#pragma unroll
    for (int off = 1; off < 64; off <<= 1) {
        int nb = __shfl_up(scan, off);
        if (lane >= off) scan += nb;
    }
    int d = __shfl(scan, 63);                    // total degree
    int excl = scan - c;                         // this lane's chunk offset
    const int* chunk = slots + n * NROW + lane * SLOTS;   // wave spans 3 KB row
    float4 xs = make_float4(0.f, 0.f, 0.f, 0.f);
    for (int q = 0; q < c; q++) {
        int src = chunk[q];
        float4 xv = ((const float4*)x)[src];
        xs.x += xv.x; xs.y += xv.y; xs.z += xv.z; xs.w += xv.w;
        int pos = excl + q;
        if (pos < CSTRIDE) compact[n * CSTRIDE + pos] = src;
    }
#pragma unroll
    for (int off = 1; off < 64; off <<= 1) {     // butterfly reduce float4
        xs.x += __shfl_xor(xs.x, off);
        xs.y += __shfl_xor(xs.y, off);
        xs.z += __shfl_xor(xs.z, off);
        xs.w += __shfl_xor(xs.w, off);
    }
    if (d > CSTRIDE) d = CSTRIDE;
    if (lane == 0) deg[n] = d;
    float inv = 1.f / fmaxf((float)d, 1.f);
    float m0 = xs.x * inv, m1 = xs.y * inv, m2 = xs.z * inv, m3 = xs.w * inv;
    float4 xn = ((const float4*)x)[n];
    float v = bl1[lane]
            + m0 * Wl1T[lane] + m1 * Wl1T[64 + lane]
            + m2 * Wl1T[128 + lane] + m3 * Wl1T[192 + lane]
            + xn.x * Wr1T[lane] + xn.y * Wr1T[64 + lane]
            + xn.z * Wr1T[128 + lane] + xn.w * Wr1T[192 + lane];
    h1[n * 64 + lane] = fmaxf(v, 0.f);
}

// ---------- dispatch 3: layer 2 (64->64) fused with h_part = h2 @ Wc1[:,:64].T ----------
__global__ __launch_bounds__(256) void layer2_kernel(
        const float* __restrict__ h1, const int* __restrict__ deg,
        const int* __restrict__ compact,
        const float* __restrict__ Wl2T, const float* __restrict__ bl2,
        const float* __restrict__ Wr2T, const float* __restrict__ Wc1hT,
        float* __restrict__ h_part) {
    int h = threadIdx.x & 63, grp = threadIdx.x >> 6;
    int n = blockIdx.x * 4 + grp;
    int d = deg[n];
    const int* bucket = compact + n * CSTRIDE;
    float a0 = 0.f, a1 = 0.f, a2 = 0.f, a3 = 0.f;
    int j = 0;
    for (; j + 4 <= d; j += 4) {
        int e0 = bucket[j], e1 = bucket[j + 1], e2 = bucket[j + 2], e3 = bucket[j + 3];
        a0 += h1[e0 * 64 + h];
        a1 += h1[e1 * 64 + h];
        a2 += h1[e2 * 64 + h];
        a3 += h1[e3 * 64 + h];
    }
    for (; j < d; j++) a0 += h1[bucket[j] * 64 + h];
    float m = (a0 + a1 + a2 + a3) / fmaxf((float)d, 1.f);

    __shared__ float shm[4][64], shh[4][64], shh2[4][64];
    shm[grp][h] = m;
    shh[grp][h] = h1[n * 64 + h];
    __syncthreads();
    float v = bl2[h];
#pragma unroll
    for (int k = 0; k < 64; k++)
        v += shm[grp][k] * Wl2T[k * 64 + h] + shh[grp][k] * Wr2T[k * 64 + h];
    shh2[grp][h] = fmaxf(v, 0.f);
    __syncthreads();
    float p = 0.f;
#pragma unroll
    for (int k = 0; k < 64; k++) p += shh2[grp][k] * Wc1hT[k * 64 + h];
    h_part[n * 64 + h] = p;
}

// ---------- dispatch 4: scores[b,n] = sum_h relu(hp[n,h]+tp[b,h])*Wc2[h] + bc2 ----------
__global__ __launch_bounds__(256) void scores_kernel(
        const float* __restrict__ h_part, const float* __restrict__ t_part,
        const float* __restrict__ Wc2, const float* __restrict__ bc2,
        float* __restrict__ out) {
    int tid = threadIdx.x;
    int n = blockIdx.x * 256 + tid;
    bool valid = n < N_NODES;
    int nn = valid ? n : (N_NODES - 1);
    float hr[64];
    const float4* hp = (const float4*)(h_part + nn * 64);
#pragma unroll
    for (int i = 0; i < 16; i++) {
        float4 v = hp[i];
        hr[4 * i + 0] = v.x; hr[4 * i + 1] = v.y;
        hr[4 * i + 2] = v.z; hr[4 * i + 3] = v.w;
    }
    float b2 = bc2[0];
    int b0 = blockIdx.y * 8;
    for (int bb = 0; bb < 8; bb++) {
        const float* tp = t_part + (b0 + bb) * 64;   // wave-uniform -> scalar loads
        float acc = 0.f;
#pragma unroll
        for (int h = 0; h < 64; h++)
            acc = fmaf(fmaxf(hr[h] + tp[h], 0.f), Wc2[h], acc);
        if (valid) out[(b0 + bb) * N_NODES + n] = acc + b2;   // 1 KB per wave, coalesced
    }
}

// ---------- launch ----------
extern "C" void kernel_launch(void* const* d_in, const int* in_sizes, int n_in,
                              void* d_out, int out_size, void* d_ws, size_t ws_size,
                              hipStream_t stream) {
    const float* x    = (const float*)d_in[0];
    const int*   ei   = (const int*)d_in[1];
    const float* task = (const float*)d_in[2];
    const float* Wl1  = (const float*)d_in[3];
    const float* bl1  = (const float*)d_in[4];
    const float* Wr1  = (const float*)d_in[5];
    const float* Wl2  = (const float*)d_in[6];
    const float* bl2  = (const float*)d_in[7];
    const float* Wr2  = (const float*)d_in[8];
    const float* Wt1  = (const float*)d_in[9];
    const float* bt1  = (const float*)d_in[10];
    const float* Wt2  = (const float*)d_in[11];
    const float* bt2  = (const float*)d_in[12];
    const float* Wc1  = (const float*)d_in[13];
    const float* bc1  = (const float*)d_in[14];
    const float* Wc2  = (const float*)d_in[15];
    const float* bc2  = (const float*)d_in[16];
    float* out = (float*)d_out;

    char* ws = (char*)d_ws;
    int*   slots   = (int*)(ws + 0);
    int*   cnt     = (int*)(ws + 15360000);
    int*   compact = (int*)(ws + 16640000);
    int*   deg     = (int*)(ws + 18560000);
    float* h1      = (float*)(ws + 18580000);
    float* h_part  = (float*)(ws + 19860000);
    float* t_part  = (float*)(ws + 21140000);
    float* Wl1T  = (float*)(ws + 21271072);
    float* Wr1T  = (float*)(ws + 21272096);
    float* Wl2T  = (float*)(ws + 21273120);
    float* Wr2T  = (float*)(ws + 21289504);
    float* Wc1hT = (float*)(ws + 21305888);

    sort_kernel<<<NSL + 4 + BATCH / 4, 256, 0, stream>>>(
        ei, task, Wt1, bt1, Wt2, bt2, Wc1, bc1, Wl1, Wr1, Wl2, Wr2,
        slots, cnt, t_part, Wl1T, Wr1T, Wl2T, Wr2T, Wc1hT);
    layer1_kernel<<<N_NODES / 4, 256, 0, stream>>>(x, slots, cnt, Wl1T, bl1, Wr1T,
                                                   deg, compact, h1);
    layer2_kernel<<<N_NODES / 4, 256, 0, stream>>>(h1, deg, compact, Wl2T, bl2, Wr2T,
                                                   Wc1hT, h_part);
    scores_kernel<<<dim3(20, 64), 256, 0, stream>>>(h_part, t_part, Wc2, bc2, out);
}